// Round 1
// baseline (5865.953 us; speedup 1.0000x reference)
//
#include <hip/hip_runtime.h>
#include <hip/hip_bf16.h>
#include <cstdint>
#include <cstddef>

#define BATCH 2
#define SEQ   4096
#define DIM   1024
#define NHEAD 16
#define HDIM  64
#define NBLK  64
#define NMID  62
#define NRAND 3
#define NLAYER 4
#define FFDIM 4096
#define ROWS  (BATCH*SEQ)   // 8192

using f32x4 = __attribute__((ext_vector_type(4))) float;
using s16x8 = __attribute__((ext_vector_type(8))) short;
using s16x4 = __attribute__((ext_vector_type(4))) short;

__device__ inline float bf2f(short s) {
    unsigned u = ((unsigned)(unsigned short)s) << 16;
    union { unsigned u; float f; } cv; cv.u = u; return cv.f;
}
__device__ inline short f2bf(float f) {
    union { float f; unsigned u; } cv; cv.f = f;
    unsigned u = cv.u;
    unsigned r = (u + 0x7fffu + ((u >> 16) & 1u)) >> 16;  // RNE
    return (short)r;
}
__device__ inline float gelu_f(float x) {
    float u = 0.7978845608028654f * (x + 0.044715f * x * x * x);
    return 0.5f * x * (1.f + tanhf(u));
}

// ---------------------------------------------------------------- embedding
__global__ __launch_bounds__(256) void embed_kernel(
    const int* __restrict__ ids, const float* __restrict__ emb, float* __restrict__ x)
{
    int row = blockIdx.x;
    int id  = ids[row];
    ((float4*)x)[(size_t)row * 256 + threadIdx.x] =
        ((const float4*)emb)[(size_t)id * 256 + threadIdx.x];
}

// ---------------------------------------------------------------- neg mask
__global__ __launch_bounds__(256) void neg_kernel(
    const int* __restrict__ mask, float* __restrict__ neg)
{
    int i = blockIdx.x * 256 + threadIdx.x;
    if (i < ROWS) neg[i] = (1.f - (float)mask[i]) * -1e9f;
}

// ---------------------------------------------------------------- layernorm (row=1024)
// OUTBF=1: write bf16 (shorts). OUTBF=0: write fp32.
template<int OUTBF>
__global__ __launch_bounds__(256) void ln_kernel(
    const float* __restrict__ x, const float* __restrict__ g,
    const float* __restrict__ bia, void* __restrict__ out)
{
    __shared__ float s1[4], s2[4];
    int row = blockIdx.x, t = threadIdx.x;
    const float* xr = x + (size_t)row * DIM;
    float4 v = ((const float4*)xr)[t];
    float s = v.x + v.y + v.z + v.w;
    #pragma unroll
    for (int o = 32; o > 0; o >>= 1) s += __shfl_xor(s, o, 64);
    if ((t & 63) == 0) s1[t >> 6] = s;
    __syncthreads();
    float mu = (s1[0] + s1[1] + s1[2] + s1[3]) * (1.f / DIM);
    float dx = v.x - mu, dy = v.y - mu, dz = v.z - mu, dw = v.w - mu;
    float q = dx*dx + dy*dy + dz*dz + dw*dw;
    #pragma unroll
    for (int o = 32; o > 0; o >>= 1) q += __shfl_xor(q, o, 64);
    if ((t & 63) == 0) s2[t >> 6] = q;
    __syncthreads();
    float var = (s2[0] + s2[1] + s2[2] + s2[3]) * (1.f / DIM);
    float rs  = rsqrtf(var + 1e-5f);
    float4 gg = ((const float4*)g)[t];
    float4 bb = ((const float4*)bia)[t];
    float o0 = dx * rs * gg.x + bb.x;
    float o1 = dy * rs * gg.y + bb.y;
    float o2 = dz * rs * gg.z + bb.z;
    float o3 = dw * rs * gg.w + bb.w;
    if (OUTBF) {
        s16x4 ov = { f2bf(o0), f2bf(o1), f2bf(o2), f2bf(o3) };
        ((s16x4*)out)[(size_t)row * (DIM/4) + t] = ov;
    } else {
        float4 ov = { o0, o1, o2, o3 };
        ((float4*)out)[(size_t)row * (DIM/4) + t] = ov;
    }
}

// ---------------------------------------------------------------- weight transpose + bf16
// W: (K x N) fp32 row-major  ->  Wt: (N x K) bf16 row-major
__global__ __launch_bounds__(256) void wconv_kernel(
    const float* __restrict__ W, short* __restrict__ Wt, int K, int N)
{
    __shared__ float tile[32][33];
    int k0 = blockIdx.x * 32, n0 = blockIdx.y * 32;
    int t = threadIdx.x;
    int r = t >> 3, c = (t & 7) * 4;
    float4 v = *(const float4*)(W + (size_t)(k0 + r) * N + n0 + c);
    tile[r][c+0] = v.x; tile[r][c+1] = v.y; tile[r][c+2] = v.z; tile[r][c+3] = v.w;
    __syncthreads();
    s16x4 ov;
    #pragma unroll
    for (int jj = 0; jj < 4; ++jj) ov[jj] = f2bf(tile[c + jj][r]);
    *(s16x4*)(Wt + (size_t)(n0 + r) * K + k0 + c) = ov;
}

// ---------------------------------------------------------------- GEMM (bf16 MFMA)
// C[M,N] = A[M,K](bf16) * Bt[N,K]^T(bf16) + bias
// EPI 0: out bf16 ; 1: out bf16 + gelu ; 2: out fp32 + residual add
template<int EPI>
__global__ __launch_bounds__(256) void gemm_kernel(
    const short* __restrict__ A, const short* __restrict__ Bt,
    const float* __restrict__ bias, const float* __restrict__ resid,
    void* __restrict__ Cout, int M, int N, int K)
{
    __shared__ short As[128 * 64];
    __shared__ short Bs[128 * 64];
    const int t = threadIdx.x;
    const int m0 = blockIdx.x * 128, n0 = blockIdx.y * 128;
    const int lane = t & 63, wave = t >> 6;
    const int wr = (wave >> 1) * 64, wc = (wave & 1) * 64;
    const int srow = t >> 3;           // 0..31
    const int scolb = (t & 7) * 16;    // byte col within 128B row

    f32x4 acc[4][4];
    #pragma unroll
    for (int m = 0; m < 4; ++m)
        #pragma unroll
        for (int n = 0; n < 4; ++n)
            acc[m][n] = f32x4{0.f, 0.f, 0.f, 0.f};

    const short* Arow = A  + (size_t)(m0 + srow) * K + (scolb >> 1);
    const short* Brow = Bt + (size_t)(n0 + srow) * K + (scolb >> 1);

    for (int kt = 0; kt < K; kt += 64) {
        s16x8 ra[4], rb[4];
        #pragma unroll
        for (int p = 0; p < 4; ++p) {
            ra[p] = *(const s16x8*)(Arow + (size_t)(p * 32) * K + kt);
            rb[p] = *(const s16x8*)(Brow + (size_t)(p * 32) * K + kt);
        }
        __syncthreads();   // previous tile's MFMA reads done
        #pragma unroll
        for (int p = 0; p < 4; ++p) {
            int row = p * 32 + srow;
            int boff = row * 128 + (scolb ^ ((row & 7) << 4));  // XOR swizzle
            *(s16x8*)((char*)As + boff) = ra[p];
            *(s16x8*)((char*)Bs + boff) = rb[p];
        }
        __syncthreads();
        #pragma unroll
        for (int kk = 0; kk < 2; ++kk) {
            s16x8 af[4], bfr[4];
            #pragma unroll
            for (int i = 0; i < 4; ++i) {
                int cb = kk * 64 + ((lane >> 4) << 4);
                int r  = wr + i * 16 + (lane & 15);
                af[i]  = *(const s16x8*)((const char*)As + r * 128 + (cb ^ ((r & 7) << 4)));
                int r2 = wc + i * 16 + (lane & 15);
                bfr[i] = *(const s16x8*)((const char*)Bs + r2 * 128 + (cb ^ ((r2 & 7) << 4)));
            }
            #pragma unroll
            for (int m = 0; m < 4; ++m)
                #pragma unroll
                for (int n = 0; n < 4; ++n)
                    acc[m][n] = __builtin_amdgcn_mfma_f32_16x16x32_bf16(
                        af[m], bfr[n], acc[m][n], 0, 0, 0);
        }
    }

    const int rbase = m0 + wr + ((lane >> 4) << 2);
    const int cbase = n0 + wc + (lane & 15);
    #pragma unroll
    for (int m = 0; m < 4; ++m) {
        #pragma unroll
        for (int n = 0; n < 4; ++n) {
            #pragma unroll
            for (int j = 0; j < 4; ++j) {
                int row = rbase + m * 16 + j;
                int col = cbase + n * 16;
                float val = acc[m][n][j] + bias[col];
                size_t idx = (size_t)row * N + col;
                if (EPI == 1) val = gelu_f(val);
                if (EPI == 2) ((float*)Cout)[idx] = val + resid[idx];
                else          ((short*)Cout)[idx] = f2bf(val);
            }
        }
    }
}

// ---------------------------------------------------------------- middle-block attention
// grid (NMID, H, B); 256 threads. q-block n=j+1 attends blocks {n-1,n,n+1,0,63,r0,r1,r2}.
__global__ __launch_bounds__(256) void attn_middle(
    const short* __restrict__ q, const short* __restrict__ k, const short* __restrict__ v,
    const float* __restrict__ neg, const int* __restrict__ rand_attn, short* __restrict__ ctx)
{
    __shared__ float Qs[64][65];
    __shared__ float KVs[64][65];
    __shared__ float Ps[64][65];
    __shared__ float redm[64][9];
    __shared__ float reds[64][9];
    __shared__ float kmask[64];

    const int j = blockIdx.x, h = blockIdx.y, b = blockIdx.z;
    const int n = j + 1;
    const int t = threadIdx.x;

    {   // stage Q (scaled by 1/sqrt(64))
        int row = t >> 2, c0 = (t & 3) * 16;
        const short* src = q + ((size_t)(b * SEQ + n * 64 + row)) * DIM + h * HDIM + c0;
        s16x8 a = ((const s16x8*)src)[0];
        s16x8 bb = ((const s16x8*)src)[1];
        #pragma unroll
        for (int i = 0; i < 8; ++i) {
            Qs[row][c0 + i]     = bf2f(a[i])  * 0.125f;
            Qs[row][c0 + 8 + i] = bf2f(bb[i]) * 0.125f;
        }
    }
    int kbl[8];
    kbl[0] = n - 1; kbl[1] = n; kbl[2] = n + 1; kbl[3] = 0; kbl[4] = NBLK - 1;
    {
        const int* ra = rand_attn + ((size_t)h * NMID + j) * NRAND;
        kbl[5] = ra[0]; kbl[6] = ra[1]; kbl[7] = ra[2];
    }
    const int rp = t >> 3, kg = t & 7;
    const int r0 = rp * 2, r1 = r0 + 1;
    float mr0 = -1e30f, mr1 = -1e30f, l0 = 0.f, l1 = 0.f;
    float c0a[8] = {0,0,0,0,0,0,0,0}, c1a[8] = {0,0,0,0,0,0,0,0};

    #pragma unroll 1
    for (int ib = 0; ib < 8; ++ib) {
        int kbn = kbl[ib];
        {   // stage K
            int row = t >> 2, cc = (t & 3) * 16;
            const short* src = k + ((size_t)(b * SEQ + kbn * 64 + row)) * DIM + h * HDIM + cc;
            s16x8 a = ((const s16x8*)src)[0];
            s16x8 bb = ((const s16x8*)src)[1];
            #pragma unroll
            for (int i = 0; i < 8; ++i) {
                KVs[row][cc + i]     = bf2f(a[i]);
                KVs[row][cc + 8 + i] = bf2f(bb[i]);
            }
            if (t < 64) kmask[t] = neg[b * SEQ + kbn * 64 + t];
        }
        __syncthreads();
        float sv0[8], sv1[8];
        #pragma unroll
        for (int kk = 0; kk < 8; ++kk) { sv0[kk] = 0.f; sv1[kk] = 0.f; }
        for (int d = 0; d < 64; ++d) {
            float qa = Qs[r0][d], qb2 = Qs[r1][d];
            #pragma unroll
            for (int kk = 0; kk < 8; ++kk) {
                float kv = KVs[kg * 8 + kk][d];
                sv0[kk] = fmaf(qa,  kv, sv0[kk]);
                sv1[kk] = fmaf(qb2, kv, sv1[kk]);
            }
        }
        float lm0 = -1e30f, lm1 = -1e30f;
        #pragma unroll
        for (int kk = 0; kk < 8; ++kk) {
            float msk = kmask[kg * 8 + kk];
            sv0[kk] += msk; sv1[kk] += msk;
            lm0 = fmaxf(lm0, sv0[kk]); lm1 = fmaxf(lm1, sv1[kk]);
        }
        redm[r0][kg] = lm0; redm[r1][kg] = lm1;
        __syncthreads();   // all K reads done; maxes ready
        float mn0 = mr0, mn1 = mr1;
        #pragma unroll
        for (int i = 0; i < 8; ++i) {
            mn0 = fmaxf(mn0, redm[r0][i]);
            mn1 = fmaxf(mn1, redm[r1][i]);
        }
        float ls0 = 0.f, ls1 = 0.f;
        #pragma unroll
        for (int kk = 0; kk < 8; ++kk) {
            float p0 = __expf(sv0[kk] - mn0), p1 = __expf(sv1[kk] - mn1);
            Ps[r0][kg * 8 + kk] = p0; Ps[r1][kg * 8 + kk] = p1;
            ls0 += p0; ls1 += p1;
        }
        reds[r0][kg] = ls0; reds[r1][kg] = ls1;
        {   // stage V (K reads completed at previous barrier)
            int row = t >> 2, cc = (t & 3) * 16;
            const short* src = v + ((size_t)(b * SEQ + kbn * 64 + row)) * DIM + h * HDIM + cc;
            s16x8 a = ((const s16x8*)src)[0];
            s16x8 bb = ((const s16x8*)src)[1];
            #pragma unroll
            for (int i = 0; i < 8; ++i) {
                KVs[row][cc + i]     = bf2f(a[i]);
                KVs[row][cc + 8 + i] = bf2f(bb[i]);
            }
        }
        __syncthreads();   // V, Ps, reds ready
        float f0 = __expf(mr0 - mn0), f1 = __expf(mr1 - mn1);
        mr0 = mn0; mr1 = mn1;
        float ps0 = 0.f, ps1 = 0.f;
        #pragma unroll
        for (int i = 0; i < 8; ++i) { ps0 += reds[r0][i]; ps1 += reds[r1][i]; }
        l0 = l0 * f0 + ps0; l1 = l1 * f1 + ps1;
        #pragma unroll
        for (int dd = 0; dd < 8; ++dd) { c0a[dd] *= f0; c1a[dd] *= f1; }
        for (int ki = 0; ki < 64; ++ki) {
            float p0 = Ps[r0][ki], p1 = Ps[r1][ki];
            #pragma unroll
            for (int dd = 0; dd < 8; ++dd) {
                float vv = KVs[ki][kg * 8 + dd];
                c0a[dd] = fmaf(p0, vv, c0a[dd]);
                c1a[dd] = fmaf(p1, vv, c1a[dd]);
            }
        }
        __syncthreads();   // PV done before next K staging
    }
    float i0 = 1.f / l0, i1 = 1.f / l1;
    s16x8 o0, o1;
    #pragma unroll
    for (int dd = 0; dd < 8; ++dd) { o0[dd] = f2bf(c0a[dd] * i0); o1[dd] = f2bf(c1a[dd] * i1); }
    size_t obase = ((size_t)(b * SEQ + n * 64)) * DIM + h * HDIM + kg * 8;
    *(s16x8*)(ctx + obase + (size_t)r0 * DIM) = o0;
    *(s16x8*)(ctx + obase + (size_t)r1 * DIM) = o1;
}

// ---------------------------------------------------------------- global-block attention
// grid (4, H, B): chunks of 32 q-rows from blocks 0 and 63, attending all S keys.
__global__ __launch_bounds__(256) void attn_global(
    const short* __restrict__ q, const short* __restrict__ k, const short* __restrict__ v,
    const float* __restrict__ neg, short* __restrict__ ctx)
{
    __shared__ float Qs[32][65];
    __shared__ float KVs[64][65];
    __shared__ float Ps[32][65];
    __shared__ float redm[32][9];
    __shared__ float reds[32][9];
    __shared__ float kmask[64];

    const int c = blockIdx.x, h = blockIdx.y, b = blockIdx.z;
    const int q0 = (c < 2) ? c * 32 : (SEQ - 128 + (c - 2) * 32 + 64); // 0,32,4032,4064
    const int t = threadIdx.x;

    {   // stage Q scaled (32 x 64)
        int row = t >> 3, cc = (t & 7) * 8;
        const short* src = q + ((size_t)(b * SEQ + q0 + row)) * DIM + h * HDIM + cc;
        s16x8 a = *(const s16x8*)src;
        #pragma unroll
        for (int i = 0; i < 8; ++i) Qs[row][cc + i] = bf2f(a[i]) * 0.125f;
    }
    const int r = t >> 3, kg = t & 7;
    float mr = -1e30f, lsum = 0.f;
    float ca[8] = {0,0,0,0,0,0,0,0};

    #pragma unroll 1
    for (int kbn = 0; kbn < NBLK; ++kbn) {
        {   // stage K
            int row = t >> 2, cc = (t & 3) * 16;
            const short* src = k + ((size_t)(b * SEQ + kbn * 64 + row)) * DIM + h * HDIM + cc;
            s16x8 a = ((const s16x8*)src)[0];
            s16x8 bb = ((const s16x8*)src)[1];
            #pragma unroll
            for (int i = 0; i < 8; ++i) {
                KVs[row][cc + i]     = bf2f(a[i]);
                KVs[row][cc + 8 + i] = bf2f(bb[i]);
            }
            if (t < 64) kmask[t] = neg[b * SEQ + kbn * 64 + t];
        }
        __syncthreads();
        float sv[8];
        #pragma unroll
        for (int kk = 0; kk < 8; ++kk) sv[kk] = 0.f;
        for (int d = 0; d < 64; ++d) {
            float qv = Qs[r][d];
            #pragma unroll
            for (int kk = 0; kk < 8; ++kk)
                sv[kk] = fmaf(qv, KVs[kg * 8 + kk][d], sv[kk]);
        }
        float lm = -1e30f;
        #pragma unroll
        for (int kk = 0; kk < 8; ++kk) {
            sv[kk] += kmask[kg * 8 + kk];
            lm = fmaxf(lm, sv[kk]);
        }
        redm[r][kg] = lm;
        __syncthreads();
        float mn = mr;
        #pragma unroll
        for (int i = 0; i < 8; ++i) mn = fmaxf(mn, redm[r][i]);
        float ls = 0.f;
        #pragma unroll
        for (int kk = 0; kk < 8; ++kk) {
            float p = __expf(sv[kk] - mn);
            Ps[r][kg * 8 + kk] = p;
            ls += p;
        }
        reds[r][kg] = ls;
        {   // stage V
            int row = t >> 2, cc = (t & 3) * 16;
            const short* src = v + ((size_t)(b * SEQ + kbn * 64 + row)) * DIM + h * HDIM + cc;
            s16x8 a = ((const s16x8*)src)[0];
            s16x8 bb = ((const s16x8*)src)[1];
            #pragma unroll
            for (int i = 0; i < 8; ++i) {
                KVs[row][cc + i]     = bf2f(a[i]);
                KVs[row][cc + 8 + i] = bf2f(bb[i]);
            }
        }
        __syncthreads();
        float f = __expf(mr - mn);
        mr = mn;
        float ps = 0.f;
        #pragma unroll
        for (int i = 0; i < 8; ++i) ps += reds[r][i];
        lsum = lsum * f + ps;
        #pragma unroll
        for (int dd = 0; dd < 8; ++dd) ca[dd] *= f;
        for (int ki = 0; ki < 64; ++ki) {
            float p = Ps[r][ki];
            #pragma unroll
            for (int dd = 0; dd < 8; ++dd)
                ca[dd] = fmaf(p, KVs[ki][kg * 8 + dd], ca[dd]);
        }
        __syncthreads();
    }
    float inv = 1.f / lsum;
    s16x8 o;
    #pragma unroll
    for (int dd = 0; dd < 8; ++dd) o[dd] = f2bf(ca[dd] * inv);
    *(s16x8*)(ctx + ((size_t)(b * SEQ + q0 + r)) * DIM + h * HDIM + kg * 8) = o;
}

// ---------------------------------------------------------------- mean over S per (b,d)
__global__ __launch_bounds__(256) void colmean_kernel(
    const float* __restrict__ xln, float* __restrict__ feats)
{
    __shared__ float red[8][33];
    int c = blockIdx.x, b = blockIdx.y;
    int dd = threadIdx.x & 31, rg = threadIdx.x >> 5;
    const float* base = xln + (size_t)b * SEQ * DIM + c * 32 + dd;
    float s = 0.f;
    for (int rr = rg; rr < SEQ; rr += 8) s += base[(size_t)rr * DIM];
    red[rg][dd] = s;
    __syncthreads();
    if (rg == 0) {
        float tot = s;
        #pragma unroll
        for (int i = 1; i < 8; ++i) tot += red[i][dd];
        feats[b * DIM + c * 32 + dd] = tot * (1.f / SEQ);
    }
}

// ---------------------------------------------------------------- normalize + project
__global__ __launch_bounds__(256) void head_kernel(
    const float* __restrict__ feats, const float* __restrict__ projW,
    const float* __restrict__ projb, float* __restrict__ out)
{
    __shared__ float f[DIM];
    __shared__ float slots[4];
    int b = blockIdx.x, t = threadIdx.x;
    float ss = 0.f;
    for (int i = t; i < DIM; i += 256) {
        float vv = feats[b * DIM + i];
        f[i] = vv;
        ss += vv * vv;
    }
    #pragma unroll
    for (int o = 32; o > 0; o >>= 1) ss += __shfl_xor(ss, o, 64);
    if ((t & 63) == 0) slots[t >> 6] = ss;
    __syncthreads();
    float nrm = sqrtf(slots[0] + slots[1] + slots[2] + slots[3]);
    float inv = 1.f / fmaxf(nrm, 1e-12f);
    for (int o = t; o < 512; o += 256) {
        float acc = 0.f;
        for (int d = 0; d < DIM; ++d)
            acc = fmaf(f[d], projW[(size_t)d * 512 + o], acc);
        out[b * 512 + o] = acc * inv + projb[o];
    }
}

// ---------------------------------------------------------------- launch
extern "C" void kernel_launch(void* const* d_in, const int* in_sizes, int n_in,
                              void* d_out, int out_size, void* d_ws, size_t ws_size,
                              hipStream_t stream)
{
    (void)in_sizes; (void)n_in; (void)out_size; (void)ws_size;
    const int*   ids   = (const int*)d_in[0];
    const int*   amask = (const int*)d_in[1];
    const int*   rnd   = (const int*)d_in[2];
    const float* emb   = (const float*)d_in[3];
    const float* Wq    = (const float*)d_in[4];
    const float* bq    = (const float*)d_in[5];
    const float* Wk    = (const float*)d_in[6];
    const float* bk    = (const float*)d_in[7];
    const float* Wv    = (const float*)d_in[8];
    const float* bv    = (const float*)d_in[9];
    const float* Wo    = (const float*)d_in[10];
    const float* bo    = (const float*)d_in[11];
    const float* ln1g  = (const float*)d_in[12];
    const float* ln1b  = (const float*)d_in[13];
    const float* W1    = (const float*)d_in[14];
    const float* b1    = (const float*)d_in[15];
    const float* W2    = (const float*)d_in[16];
    const float* b2    = (const float*)d_in[17];
    const float* ln2g  = (const float*)d_in[18];
    const float* ln2b  = (const float*)d_in[19];
    const float* lnfg  = (const float*)d_in[20];
    const float* lnfb  = (const float*)d_in[21];
    const float* projW = (const float*)d_in[22];
    const float* projb = (const float*)d_in[23];
    float* out = (float*)d_out;

    char* ws = (char*)d_ws;
    size_t off = 0;
    float* x    = (float*)(ws + off); off += (size_t)ROWS * DIM * 4;
    float* xn_f = (float*)(ws + off);
    short* xn_b = (short*)(ws + off); off += (size_t)ROWS * DIM * 4;
    short* qb   = (short*)(ws + off); off += (size_t)ROWS * DIM * 2;
    short* kbuf = (short*)(ws + off); off += (size_t)ROWS * DIM * 2;
    short* vbuf = (short*)(ws + off); off += (size_t)ROWS * DIM * 2;
    short* ctxb = (short*)(ws + off); off += (size_t)ROWS * DIM * 2;
    short* ffb  = (short*)(ws + off); off += (size_t)ROWS * FFDIM * 2;
    short* wt   = (short*)(ws + off); off += (size_t)FFDIM * DIM * 2;
    float* neg  = (float*)(ws + off); off += (size_t)ROWS * 4;
    float* feats= (float*)(ws + off); off += (size_t)BATCH * DIM * 4;

    embed_kernel<<<ROWS, 256, 0, stream>>>(ids, emb, x);
    neg_kernel<<<(ROWS + 255) / 256, 256, 0, stream>>>(amask, neg);

    for (int l = 0; l < NLAYER; ++l) {
        ln_kernel<1><<<ROWS, 256, 0, stream>>>(x, ln1g + l * DIM, ln1b + l * DIM, xn_b);

        wconv_kernel<<<dim3(DIM/32, DIM/32), 256, 0, stream>>>(Wq + (size_t)l*DIM*DIM, wt, DIM, DIM);
        gemm_kernel<0><<<dim3(ROWS/128, DIM/128), 256, 0, stream>>>(xn_b, wt, bq + l*DIM, nullptr, qb,   ROWS, DIM, DIM);
        wconv_kernel<<<dim3(DIM/32, DIM/32), 256, 0, stream>>>(Wk + (size_t)l*DIM*DIM, wt, DIM, DIM);
        gemm_kernel<0><<<dim3(ROWS/128, DIM/128), 256, 0, stream>>>(xn_b, wt, bk + l*DIM, nullptr, kbuf, ROWS, DIM, DIM);
        wconv_kernel<<<dim3(DIM/32, DIM/32), 256, 0, stream>>>(Wv + (size_t)l*DIM*DIM, wt, DIM, DIM);
        gemm_kernel<0><<<dim3(ROWS/128, DIM/128), 256, 0, stream>>>(xn_b, wt, bv + l*DIM, nullptr, vbuf, ROWS, DIM, DIM);

        attn_global<<<dim3(4, NHEAD, BATCH), 256, 0, stream>>>(qb, kbuf, vbuf, neg, ctxb);
        attn_middle<<<dim3(NMID, NHEAD, BATCH), 256, 0, stream>>>(qb, kbuf, vbuf, neg, rnd, ctxb);

        wconv_kernel<<<dim3(DIM/32, DIM/32), 256, 0, stream>>>(Wo + (size_t)l*DIM*DIM, wt, DIM, DIM);
        gemm_kernel<2><<<dim3(ROWS/128, DIM/128), 256, 0, stream>>>(ctxb, wt, bo + l*DIM, x, x, ROWS, DIM, DIM);

        ln_kernel<1><<<ROWS, 256, 0, stream>>>(x, ln2g + l * DIM, ln2b + l * DIM, xn_b);

        wconv_kernel<<<dim3(DIM/32, FFDIM/32), 256, 0, stream>>>(W1 + (size_t)l*DIM*FFDIM, wt, DIM, FFDIM);
        gemm_kernel<1><<<dim3(ROWS/128, FFDIM/128), 256, 0, stream>>>(xn_b, wt, b1 + l*FFDIM, nullptr, ffb, ROWS, FFDIM, DIM);
        wconv_kernel<<<dim3(FFDIM/32, DIM/32), 256, 0, stream>>>(W2 + (size_t)l*FFDIM*DIM, wt, FFDIM, DIM);
        gemm_kernel<2><<<dim3(ROWS/128, DIM/128), 256, 0, stream>>>(ffb, wt, b2 + l*DIM, x, x, ROWS, DIM, FFDIM);
    }

    ln_kernel<0><<<ROWS, 256, 0, stream>>>(x, lnfg, lnfb, xn_f);
    colmean_kernel<<<dim3(32, BATCH), 256, 0, stream>>>(xn_f, feats);
    head_kernel<<<BATCH, 256, 0, stream>>>(feats, projW, projb, out);
}